// Round 10
// baseline (365.837 us; speedup 1.0000x reference)
//
#include <hip/hip_runtime.h>
#include <cstdint>
#include <cmath>

#define MB (1024ull * 1024ull)

typedef unsigned short u16;
typedef __attribute__((ext_vector_type(8))) short short8;
typedef __attribute__((ext_vector_type(4))) float f32x4;

enum { M_TANH = 0, M_ZRE = 1, M_QKVF = 2, M_SCALE = 3, M_PVRAW = 4, M_F32 = 5 };

__device__ __forceinline__ u16 f2b(float f) {
  union { float f; uint32_t u; } v; v.f = f;
  uint32_t r = v.u + 0x7FFFu + ((v.u >> 16) & 1u);
  return (u16)(r >> 16);
}
__device__ __forceinline__ float b2f(u16 u) {
  union { uint32_t u; float f; } v; v.u = ((uint32_t)u) << 16;
  return v.f;
}

typedef __attribute__((address_space(3))) uint32_t lds_u32;
typedef const __attribute__((address_space(1))) uint32_t glb_u32;

__device__ __forceinline__ void gload16(const void* g, void* l) {
  __builtin_amdgcn_global_load_lds((glb_u32*)g, (lds_u32*)l, 16, 0, 0);
}

#define SBAR asm volatile("s_barrier" ::: "memory")

// ============ 256x256 8-phase GEMM (plain-HIP port of the m201 template) ============
// 512 thr, 8 waves (2M x 4N), per-wave C = 128x64 (acc[8][4] f32x4), BK=64.
// LDS: As/Bs [2 slots][256*64] bf16 (128 KB). Slot = kt&1 (kt0 even->0, kt1->1).
// Phase = { ds_read subtile ; stage 1 half-tile (2 gload_lds) ; s_barrier ;
//           setprio(1) 16 MFMA (one C-quadrant x K=64) setprio(0) ; s_barrier }.
// Stage stream P1..P8: A0(kt1) A1(kt1) B0(kt0+2) B1(kt0+2) A0(kt0+2) A1(kt0+2)
//                      B0(kt1+2) B1(kt1+2)  -- each region staged 2 phases after
// its last reader, >=3 phases before its first reader.
// vmcnt(4) ONLY at P4/P8 (retires all halves the next K-tile needs; 4 loads stay
// in flight). LDS swizzle: 16B-chunk c of row r lives at c^(r&7) (rule 21: applied
// to BOTH the pre-swizzled global source and the ds_read address; gload dest linear).
template <int MODE>
__global__ __launch_bounds__(512, 2) void gemm8(const u16* __restrict__ A,
                                                const u16* __restrict__ B,
                                                const float* __restrict__ bias,
                                                const u16* __restrict__ A2,
                                                const u16* __restrict__ B2,
                                                const float* __restrict__ bias2,
                                                u16* __restrict__ Cb,
                                                u16* __restrict__ Cb2,
                                                u16* __restrict__ Cb3,
                                                float* __restrict__ Cf,
                                                int K, int lda, int ldb, float scale) {
  __shared__ u16 As[2][256 * 64];
  __shared__ u16 Bs[2][256 * 64];
  const int tid = threadIdx.x;
  const int wid = tid >> 6, lane = tid & 63;
  const int wr = wid >> 2, wc = wid & 3;
  const int ar = lane & 15;

  // XCD-aware bijective block swizzle (all nwg here are multiples of 8)
  const int gx = gridDim.x, nwg = gx * gridDim.y;
  int id = blockIdx.y * gx + blockIdx.x;
  if ((nwg & 7) == 0) id = (id & 7) * (nwg >> 3) + (id >> 3);
  const int bm = (id / gx) * 256, bn = (id % gx) * 256;

  const bool isf = (MODE == M_QKVF) && (bn >= 3072);
  const u16* Ab = isf ? A2 : A;
  const u16* Bb = isf ? B2 : B;
  const int bnl = isf ? bn - 3072 : bn;
  const int kofs = (MODE == M_PVRAW) ? (int)blockIdx.z * K : 0;

  const int NKT = K >> 6;  // K-tiles of 64 (always even here)

  auto stA = [&](int slot, int half, int kt) {
    if (kt >= NKT) return;
#pragma unroll
    for (int l = 0; l < 2; ++l) {
      const int grow = half * 128 + l * 64 + (tid >> 3);
      const u16* src = Ab + (size_t)(bm + grow) * lda + kofs + kt * 64 +
                       (((tid & 7) ^ (grow & 7)) << 3);
      gload16(src, &As[slot][(half * 128 + l * 64) * 64 + tid * 8]);
    }
  };
  auto stB = [&](int slot, int half, int kt) {
    if (kt >= NKT) return;
#pragma unroll
    for (int l = 0; l < 2; ++l) {
      const int grow = half * 128 + l * 64 + (tid >> 3);
      const u16* src = Bb + (size_t)(bnl + grow) * ldb + kofs + kt * 64 +
                       (((tid & 7) ^ (grow & 7)) << 3);
      gload16(src, &Bs[slot][(half * 128 + l * 64) * 64 + tid * 8]);
    }
  };

  f32x4 acc[8][4];
#pragma unroll
  for (int i = 0; i < 8; ++i)
#pragma unroll
    for (int j = 0; j < 4; ++j) acc[i][j] = (f32x4){0.f, 0.f, 0.f, 0.f};

  short8 Ar[4][2], B0r[2][2], B1r[2][2];

  auto rdA4 = [&](int slot, int rbase) {
#pragma unroll
    for (int rg = 0; rg < 4; ++rg)
#pragma unroll
      for (int kk = 0; kk < 2; ++kk) {
        const int row = wr * 128 + rbase + rg * 16 + ar;
        const int kc = kk * 4 + (lane >> 4);
        Ar[rg][kk] = *reinterpret_cast<const short8*>(
            &As[slot][row * 64 + ((kc ^ (row & 7)) << 3)]);
      }
  };
  auto rdB2 = [&](int slot, int cbase, short8 (&Br)[2][2]) {
#pragma unroll
    for (int cg = 0; cg < 2; ++cg)
#pragma unroll
      for (int kk = 0; kk < 2; ++kk) {
        const int row = wc * 64 + cbase + cg * 16 + ar;
        const int kc = kk * 4 + (lane >> 4);
        Br[cg][kk] = *reinterpret_cast<const short8*>(
            &Bs[slot][row * 64 + ((kc ^ (row & 7)) << 3)]);
      }
  };
  auto quad = [&](int qr, int qc, short8 (&Br)[2][2]) {
    __builtin_amdgcn_s_setprio(1);
#pragma unroll
    for (int rg = 0; rg < 4; ++rg)
#pragma unroll
      for (int cg = 0; cg < 2; ++cg)
#pragma unroll
        for (int kk = 0; kk < 2; ++kk)
          acc[qr * 4 + rg][qc * 2 + cg] = __builtin_amdgcn_mfma_f32_16x16x32_bf16(
              Ar[rg][kk], Br[cg][kk], acc[qr * 4 + rg][qc * 2 + cg], 0, 0, 0);
    __builtin_amdgcn_s_setprio(0);
  };

  // prologue: tile0 complete (8 loads) + B halves of tile1 (4 loads)
  stA(0, 0, 0); stA(0, 1, 0); stB(0, 0, 0); stB(0, 1, 0);
  stB(1, 0, 1); stB(1, 1, 1);
  asm volatile("s_waitcnt vmcnt(4)" ::: "memory");  // tile0 landed; tile1-B in flight
  SBAR;

  const int NIT = NKT >> 1;
  for (int i = 0; i < NIT; ++i) {
    const int kt1 = 2 * i + 1, kt2a = 2 * i + 2, kt2b = 2 * i + 3;
    const bool last = (i + 1 == NIT);
    // P1: q(0,0) of kt0 | stage A0(kt1)
    rdA4(0, 0); rdB2(0, 0, B0r);
    stA(1, 0, kt1);
    SBAR; quad(0, 0, B0r); SBAR;
    // P2: q(0,1) | stage A1(kt1)
    rdB2(0, 32, B1r);
    stA(1, 1, kt1);
    SBAR; quad(0, 1, B1r); SBAR;
    // P3: q(1,1) | stage B0(kt0+2)  (kt0's B0 fully read at P2)
    rdA4(0, 64);
    stB(0, 0, kt2a);
    SBAR; quad(1, 1, B1r); SBAR;
    // P4: q(1,0) | stage B1(kt0+2); counted vmcnt -> kt1 fully landed for P5
    stB(0, 1, kt2a);
    if (last) asm volatile("s_waitcnt vmcnt(0)" ::: "memory");
    else      asm volatile("s_waitcnt vmcnt(4)" ::: "memory");
    SBAR; quad(1, 0, B0r); SBAR;
    // P5: q(0,0) of kt1 | stage A0(kt0+2)  (kt0's A0 fully read at P3)
    rdA4(1, 0); rdB2(1, 0, B0r);
    stA(0, 0, kt2a);
    SBAR; quad(0, 0, B0r); SBAR;
    // P6: q(0,1) | stage A1(kt0+2)
    rdB2(1, 32, B1r);
    stA(0, 1, kt2a);
    SBAR; quad(0, 1, B1r); SBAR;
    // P7: q(1,1) | stage B0(kt1+2)  (kt1's B0 fully read at P6)
    rdA4(1, 64);
    stB(1, 0, kt2b);
    SBAR; quad(1, 1, B1r); SBAR;
    // P8: q(1,0) | stage B1(kt1+2); counted vmcnt -> kt0+2 fully landed for next P1
    stB(1, 1, kt2b);
    if (last) asm volatile("s_waitcnt vmcnt(0)" ::: "memory");
    else      asm volatile("s_waitcnt vmcnt(4)" ::: "memory");
    SBAR; quad(1, 0, B0r); SBAR;
  }

  float* Cfz = Cf;
  if (MODE == M_PVRAW && blockIdx.z != 0) Cfz = (float*)Cb3;

#pragma unroll
  for (int ii = 0; ii < 8; ++ii) {
    const int rb = bm + wr * 128 + ii * 16 + (lane >> 4) * 4;
#pragma unroll
    for (int j = 0; j < 4; ++j) {
      const int n = bn + wc * 64 + j * 16 + ar;
#pragma unroll
      for (int r = 0; r < 4; ++r) {
        const int m = rb + r;
        float v = acc[ii][j][r];
        if (MODE == M_TANH) {
          v = tanhf(v + bias[n]);
          Cb[(size_t)m * 2048 + n] = f2b(v);
        } else if (MODE == M_ZRE) {
          v += bias[n];
          if (n < 1024) { const float s = v / (1.f + expf(-v)); Cb[(size_t)m * 1024 + n] = f2b(s); }
          else Cb2[(size_t)m * 1024 + (n - 1024)] = f2b(v);
        } else if (MODE == M_QKVF) {
          if (isf) {
            const int nl = n - 3072;
            const float s = 1.f / (1.f + expf(-(v + bias2[nl])));
            Cb3[(size_t)m * 1024 + nl] = f2b(s);
          } else {
            v += bias[n];
            if (n < 2048) Cb[(size_t)m * 2048 + n] = f2b(v);
            else Cb2[(size_t)m * 1024 + (n - 2048)] = f2b(v);
          }
        } else if (MODE == M_SCALE) {
          Cb[(size_t)m * 4096 + n] = f2b(v * scale);
        } else if (MODE == M_PVRAW) {
          Cfz[(size_t)m * 1024 + n] = v;
        }
      }
    }
  }
}

// ============ old 2-phase 128xBNT GEMM (kept for zemaf only) ============
template <int MODE, int BNT>
__global__ __launch_bounds__(256) void gemm(const u16* __restrict__ A,
                                            const u16* __restrict__ B,
                                            const float* __restrict__ bias,
                                            u16* __restrict__ Cb,
                                            float* __restrict__ Cf,
                                            int K, int lda, int ldb) {
  constexpr int NI = 4;
  constexpr int NJ = (BNT == 128) ? 4 : 2;
  __shared__ u16 As[2][128 * 32];
  __shared__ u16 Bs[2][BNT * 32];
  const int tid = threadIdx.x;
  const int wid = tid >> 6, lane = tid & 63;
  const int gx = gridDim.x, nwg = gx * gridDim.y;
  int id = blockIdx.y * gx + blockIdx.x;
  if ((nwg & 7) == 0) id = (id & 7) * (nwg >> 3) + (id >> 3);
  const int bm = (id / gx) * 128, bn = (id % gx) * BNT;
  const int wm = wid >> 1, wn = wid & 1;
  const int rowbase = wm * 64, colbase = wn * (BNT / 2);
  const int srow = tid >> 2;
  const int schunk = (tid & 3) ^ ((srow >> 1) & 3);
  const u16* gA = A + (size_t)(bm + srow) * lda + schunk * 8;
  const u16* gB = B + (size_t)(bn + srow) * ldb + schunk * 8;
  f32x4 acc[NI][NJ];
#pragma unroll
  for (int i = 0; i < NI; ++i)
#pragma unroll
    for (int j = 0; j < NJ; ++j) acc[i][j] = (f32x4){0.f, 0.f, 0.f, 0.f};
  const int ar = lane & 15;
  const int pch = (((lane >> 4) ^ ((ar >> 1) & 3))) * 8;
  const int NT = K >> 5;
  auto stage = [&](int buf, int t) {
    const u16* a = gA + (size_t)t * 32;
    const u16* b = gB + (size_t)t * 32;
    gload16(a, &As[buf][wid * 512]);
    gload16(a + (size_t)64 * lda, &As[buf][wid * 512 + 2048]);
    gload16(b, &Bs[buf][wid * 512]);
    if (BNT == 128) gload16(b + (size_t)64 * ldb, &Bs[buf][wid * 512 + 2048]);
  };
  stage(0, 0);
  __syncthreads();
  int cur = 0;
  for (int t = 0; t < NT; ++t) {
    if (t + 1 < NT) stage(cur ^ 1, t + 1);
    short8 af[NI], bf[NJ];
#pragma unroll
    for (int i = 0; i < NI; ++i)
      af[i] = *reinterpret_cast<const short8*>(&As[cur][(rowbase + i * 16 + ar) * 32 + pch]);
#pragma unroll
    for (int j = 0; j < NJ; ++j)
      bf[j] = *reinterpret_cast<const short8*>(&Bs[cur][(colbase + j * 16 + ar) * 32 + pch]);
#pragma unroll
    for (int i = 0; i < NI; ++i)
#pragma unroll
      for (int j = 0; j < NJ; ++j)
        acc[i][j] = __builtin_amdgcn_mfma_f32_16x16x32_bf16(af[i], bf[j], acc[i][j], 0, 0, 0);
    __syncthreads();
    cur ^= 1;
  }
#pragma unroll
  for (int i = 0; i < NI; ++i) {
    const int rb = bm + rowbase + i * 16 + (lane >> 4) * 4;
#pragma unroll
    for (int j = 0; j < NJ; ++j) {
      const int n = bn + colbase + j * 16 + (lane & 15);
#pragma unroll
      for (int r = 0; r < 4; ++r) {
        const int m = rb + r;
        if (MODE == M_F32) Cf[(size_t)m * 1024 + n] = acc[i][j][r] + bias[n];
      }
    }
  }
}

// Zatp = f2b( (p0 + p1) * f )
__global__ __launch_bounds__(256) void pv_reduce(const float* __restrict__ p0,
                                                 const float* __restrict__ p1,
                                                 const u16* __restrict__ fvb,
                                                 u16* __restrict__ Zatp) {
  const int idx = blockIdx.x * 256 + threadIdx.x;
  const float4 a = reinterpret_cast<const float4*>(p0)[idx];
  const float4 b = reinterpret_cast<const float4*>(p1)[idx];
  const ushort4 f4 = reinterpret_cast<const ushort4*>(fvb)[idx];
  ushort4 o;
  o.x = f2b((a.x + b.x) * b2f(f4.x));
  o.y = f2b((a.y + b.y) * b2f(f4.y));
  o.z = f2b((a.z + b.z) * b2f(f4.z));
  o.w = f2b((a.w + b.w) * b2f(f4.w));
  reinterpret_cast<ushort4*>(Zatp)[idx] = o;
}

__global__ __launch_bounds__(256) void convert_all(
    const float* __restrict__ s0, const float* __restrict__ s1, const float* __restrict__ s2,
    const float* __restrict__ s3, const float* __restrict__ s4, const float* __restrict__ s5,
    const float* __restrict__ s6, const float* __restrict__ s7, const float* __restrict__ s8,
    u16* __restrict__ Wad, u16* __restrict__ Wze, u16* __restrict__ Wqkv,
    u16* __restrict__ Wfb, u16* __restrict__ Wzab) {
  const int idx = blockIdx.x * 256 + threadIdx.x;
  const float* src; u16* dst; int off;
  if      (idx < 524288)  { src = s0; dst = Wad;           off = idx; }
  else if (idx < 1048576) { src = s1; dst = Wad + 2097152; off = idx - 524288; }
  else if (idx < 1310720) { src = s2; dst = Wze;           off = idx - 1048576; }
  else if (idx < 1572864) { src = s3; dst = Wze + 1048576; off = idx - 1310720; }
  else if (idx < 1835008) { src = s4; dst = Wqkv;          off = idx - 1572864; }
  else if (idx < 2097152) { src = s5; dst = Wqkv + 1048576; off = idx - 1835008; }
  else if (idx < 2359296) { src = s6; dst = Wqkv + 2097152; off = idx - 2097152; }
  else if (idx < 2621440) { src = s7; dst = Wfb;           off = idx - 2359296; }
  else                    { src = s8; dst = Wzab;          off = idx - 2621440; }
  const float4 v = reinterpret_cast<const float4*>(src)[off];
  ushort4 o; o.x = f2b(v.x); o.y = f2b(v.y); o.z = f2b(v.z); o.w = f2b(v.w);
  reinterpret_cast<ushort4*>(dst)[off] = o;
}

__global__ void copy_bias(const float* __restrict__ ba, const float* __restrict__ bd,
                          const float* __restrict__ bz, const float* __restrict__ be,
                          const float* __restrict__ bq, const float* __restrict__ bk,
                          const float* __restrict__ bv,
                          float* __restrict__ bad, float* __restrict__ bze,
                          float* __restrict__ bqkv) {
  const int t = threadIdx.x;
  const float4* src; float4* dst;
  switch (blockIdx.x) {
    case 0: src = (const float4*)ba; dst = (float4*)bad; break;
    case 1: src = (const float4*)bd; dst = (float4*)(bad + 1024); break;
    case 2: src = (const float4*)bz; dst = (float4*)bze; break;
    case 3: src = (const float4*)be; dst = (float4*)(bze + 1024); break;
    case 4: src = (const float4*)bq; dst = (float4*)bqkv; break;
    case 5: src = (const float4*)bk; dst = (float4*)(bqkv + 1024); break;
    default: src = (const float4*)bv; dst = (float4*)(bqkv + 2048); break;
  }
  dst[t] = src[t];
}

__global__ __launch_bounds__(256) void concat_kern(const float* __restrict__ R,
                                                   u16* __restrict__ Rc) {
  const int idx = blockIdx.x * 256 + threadIdx.x;
  const int m = idx >> 9;
  const int c = (idx & 511) * 4;
  float4 v;
  if (c < 1024) {
    if (m > 0) v = *reinterpret_cast<const float4*>(&R[(size_t)(m - 1) * 1024 + c]);
    else v = make_float4(0.f, 0.f, 0.f, 0.f);
  } else {
    v = *reinterpret_cast<const float4*>(&R[(size_t)m * 1024 + (c - 1024)]);
  }
  ushort4 o; o.x = f2b(v.x); o.y = f2b(v.y); o.z = f2b(v.z); o.w = f2b(v.w);
  reinterpret_cast<ushort4*>(Rc)[idx] = o;
}

__global__ __launch_bounds__(256) void ema_combine(const float* __restrict__ R,
                                                   const u16* __restrict__ adb,
                                                   u16* __restrict__ REMA) {
  const int idx = blockIdx.x * 256 + threadIdx.x;
  const int m = idx >> 8, c4 = idx & 255;
  const float4 rt = reinterpret_cast<const float4*>(R)[idx];
  float4 rp = make_float4(0.f, 0.f, 0.f, 0.f);
  if (m > 0) rp = reinterpret_cast<const float4*>(R)[idx - 256];
  const ushort4 a4 = reinterpret_cast<const ushort4*>(adb)[m * 512 + c4];
  const ushort4 d4 = reinterpret_cast<const ushort4*>(adb)[m * 512 + 256 + c4];
  ushort4 o;
  { const float av = b2f(a4.x); o.x = f2b(av * rt.x + (1.f - av) * b2f(d4.x) * rp.x); }
  { const float av = b2f(a4.y); o.y = f2b(av * rt.y + (1.f - av) * b2f(d4.y) * rp.y); }
  { const float av = b2f(a4.z); o.z = f2b(av * rt.z + (1.f - av) * b2f(d4.z) * rp.z); }
  { const float av = b2f(a4.w); o.w = f2b(av * rt.w + (1.f - av) * b2f(d4.w) * rp.w); }
  reinterpret_cast<ushort4*>(REMA)[idx] = o;
}

__device__ __forceinline__ float waveMax(float v) {
#pragma unroll
  for (int o = 32; o; o >>= 1) v = fmaxf(v, __shfl_down(v, o));
  return v;
}
__device__ __forceinline__ float waveSum(float v) {
#pragma unroll
  for (int o = 32; o; o >>= 1) v += __shfl_down(v, o);
  return v;
}

__global__ __launch_bounds__(256) void softmax_rows(u16* __restrict__ S) {
  u16* p = S + (size_t)blockIdx.x * 4096;
  const int tid = threadIdx.x;
  float v[16];
#pragma unroll
  for (int j = 0; j < 4; ++j) {
    const ushort4 t = *reinterpret_cast<const ushort4*>(&p[tid * 4 + 1024 * j]);
    v[4 * j + 0] = b2f(t.x); v[4 * j + 1] = b2f(t.y);
    v[4 * j + 2] = b2f(t.z); v[4 * j + 3] = b2f(t.w);
  }
  float mx = -INFINITY;
#pragma unroll
  for (int j = 0; j < 16; ++j) mx = fmaxf(mx, v[j]);
  __shared__ float red[4];
  const float wm = waveMax(mx);
  if ((tid & 63) == 0) red[tid >> 6] = wm;
  __syncthreads();
  mx = fmaxf(fmaxf(red[0], red[1]), fmaxf(red[2], red[3]));
  __syncthreads();
  float sum = 0.f;
#pragma unroll
  for (int j = 0; j < 16; ++j) { v[j] = expf(v[j] - mx); sum += v[j]; }
  const float ws_ = waveSum(sum);
  if ((tid & 63) == 0) red[tid >> 6] = ws_;
  __syncthreads();
  const float inv = 1.f / (red[0] + red[1] + red[2] + red[3]);
#pragma unroll
  for (int j = 0; j < 4; ++j) {
    ushort4 t;
    t.x = f2b(v[4 * j + 0] * inv); t.y = f2b(v[4 * j + 1] * inv);
    t.z = f2b(v[4 * j + 2] * inv); t.w = f2b(v[4 * j + 3] * inv);
    *reinterpret_cast<ushort4*>(&p[tid * 4 + 1024 * j]) = t;
  }
}

__global__ __launch_bounds__(256) void transpose_b16(const u16* __restrict__ V,
                                                     u16* __restrict__ Vt) {
  __shared__ u16 t[64][72];
  const int bn = blockIdx.x * 64;
  const int bk = blockIdx.y * 64;
  const int tx = threadIdx.x & 15, ty = threadIdx.x >> 4;
#pragma unroll
  for (int i = 0; i < 64; i += 16) {
    const ushort4 v = *reinterpret_cast<const ushort4*>(&V[(size_t)(bk + ty + i) * 1024 + bn + tx * 4]);
    t[ty + i][tx * 4 + 0] = v.x; t[ty + i][tx * 4 + 1] = v.y;
    t[ty + i][tx * 4 + 2] = v.z; t[ty + i][tx * 4 + 3] = v.w;
  }
  __syncthreads();
#pragma unroll
  for (int i = 0; i < 64; i += 16) {
    ushort4 w;
    w.x = t[tx * 4 + 0][ty + i]; w.y = t[tx * 4 + 1][ty + i];
    w.z = t[tx * 4 + 2][ty + i]; w.w = t[tx * 4 + 3][ty + i];
    *reinterpret_cast<ushort4*>(&Vt[(size_t)(bn + ty + i) * 4096 + bk + tx * 4]) = w;
  }
}

__global__ void final_kern(const u16* __restrict__ REMAb, const u16* __restrict__ REMApb,
                           const float* __restrict__ ZEMAf,
                           const float* __restrict__ Wi, const float* __restrict__ bi,
                           const float* __restrict__ Wfin, float* __restrict__ out) {
  const int m = blockIdx.x, l = threadIdx.x;
  float si = 0.f;
#pragma unroll
  for (int j = 0; j < 16; ++j) {
    const int n = l + 64 * j;
    si += b2f(REMAb[(size_t)m * 1024 + n]) * Wi[n];
  }
#pragma unroll
  for (int o = 32; o; o >>= 1) si += __shfl_xor(si, o);
  const float im = tanhf(si + bi[0]);
  float s = 0.f;
#pragma unroll
  for (int j = 0; j < 16; ++j) {
    const int n = l + 64 * j;
    const float rp = b2f(REMApb[(size_t)m * 1024 + n]);
    const float zf = im * tanhf(rp + ZEMAf[(size_t)m * 1024 + n]) + (1.f - im) * rp;
    s += zf * Wfin[n];
  }
#pragma unroll
  for (int o = 32; o; o >>= 1) s += __shfl_down(s, o);
  if (l == 0) out[m] = 1.f / (1.f + expf(-s));
}

extern "C" void kernel_launch(void* const* d_in, const int* in_sizes, int n_in,
                              void* d_out, int out_size, void* d_ws, size_t ws_size,
                              hipStream_t stream) {
  const float* R       = (const float*)d_in[0];
  const float* W_alpha = (const float*)d_in[1];  const float* b_alpha = (const float*)d_in[2];
  const float* W_delta = (const float*)d_in[3];  const float* b_delta = (const float*)d_in[4];
  const float* W_q     = (const float*)d_in[5];  const float* b_q     = (const float*)d_in[6];
  const float* W_k     = (const float*)d_in[7];  const float* b_k     = (const float*)d_in[8];
  const float* W_v     = (const float*)d_in[9];  const float* b_v     = (const float*)d_in[10];
  const float* W_z     = (const float*)d_in[11]; const float* b_z     = (const float*)d_in[12];
  const float* W_f     = (const float*)d_in[13]; const float* b_f     = (const float*)d_in[14];
  const float* W_EMA   = (const float*)d_in[15]; const float* b_EMA   = (const float*)d_in[16];
  const float* W_z_at  = (const float*)d_in[17]; const float* b_z_at  = (const float*)d_in[18];
  const float* W_i     = (const float*)d_in[19]; const float* b_i     = (const float*)d_in[20];
  const float* W_final = (const float*)d_in[21];
  float* out = (float*)d_out;
  uint8_t* w8 = (uint8_t*)d_ws;

  // ---- workspace layout (time-multiplexed), peak ~110 MB ----
  u16*   Rc     = (u16*)(w8 + 0 * MB);     // [0,16)  concat -> adGEMM
  u16*   Zb     = (u16*)(w8 + 0 * MB);     // [0,8)   zre -> qkvf
  u16*   Zatpb  = (u16*)(w8 + 0 * MB);     // [0,8)   pv_reduce -> zemaf
  u16*   REMApb = (u16*)(w8 + 8 * MB);     // [8,16)  zre -> final
  u16*   Wad    = (u16*)(w8 + 16 * MB);    // [16,24) conv -> adGEMM
  u16*   fvb    = (u16*)(w8 + 16 * MB);    // [16,24) qkvf -> pv_reduce
  u16*   adb    = (u16*)(w8 + 24 * MB);    // [24,40) adGEMM -> ema
  float* pvp0   = (float*)(w8 + 24 * MB);  // [24,40) PV partial 0 (adb dead)
  float* ZEMAf  = (float*)(w8 + 24 * MB);  // [24,40) zemaf -> final
  u16*   Wqkv   = (u16*)(w8 + 40 * MB);    // [40,46) conv -> qkvf
  u16*   Vtb    = (u16*)(w8 + 40 * MB);    // [40,48) transpose -> PV
  u16*   Wze    = (u16*)(w8 + 46 * MB);    // [46,50) conv -> zre
  u16*   Wfb    = (u16*)(w8 + 50 * MB);    // [50,52) conv -> qkvf(f)
  u16*   Wzab   = (u16*)(w8 + 52 * MB);    // [52,54) conv -> zemaf
  u16*   REMAb  = (u16*)(w8 + 54 * MB);    // [54,62) ema -> end
  u16*   QKb    = (u16*)(w8 + 62 * MB);    // [62,78) qkvf -> scores
  float* pvp1   = (float*)(w8 + 62 * MB);  // [62,78) PV partial 1 (QKb dead)
  u16*   Vb     = (u16*)(w8 + 78 * MB);    // [78,86) qkvf -> transpose
  u16*   Sb     = (u16*)(w8 + 78 * MB);    // [78,110) scores -> PV
  float* bad    = (float*)(w8 + 110 * MB + 64 * 1024);
  float* bze    = bad + 2048;
  float* bqkv   = bze + 2048;

  const dim3 blk(256);
  convert_all<<<11264, blk, 0, stream>>>(W_alpha, W_delta, W_z, W_EMA, W_q, W_k, W_v, W_f, W_z_at,
                                         Wad, Wze, Wqkv, Wfb, Wzab);
  concat_kern<<<8192, blk, 0, stream>>>(R, Rc);
  copy_bias<<<7, blk, 0, stream>>>(b_alpha, b_delta, b_z, b_EMA, b_q, b_k, b_v, bad, bze, bqkv);

  // alpha|delta: [4096][2048] = tanh(Rc @ Wad^T + bad)   (128 blocks, 256²)
  gemm8<M_TANH><<<dim3(8, 16), 512, 0, stream>>>(
      Rc, Wad, bad, nullptr, nullptr, nullptr, adb, nullptr, nullptr, nullptr, 2048, 2048, 2048, 1.f);
  ema_combine<<<4096, blk, 0, stream>>>(R, adb, REMAb);
  // Z | REMAp: N=2048 (silu -> Zb, plain -> REMApb)   (128 blocks)
  gemm8<M_ZRE><<<dim3(8, 16), 512, 0, stream>>>(
      REMAb, Wze, bze, nullptr, nullptr, nullptr, Zb, REMApb, nullptr, nullptr, 1024, 1024, 1024, 1.f);
  // QKV + f merged: virtual N=4096 (QK->QKb, V->Vb, f->fvb)   (256 blocks)
  gemm8<M_QKVF><<<dim3(16, 16), 512, 0, stream>>>(
      Zb, Wqkv, bqkv, REMApb, Wfb, b_f, QKb, Vb, fvb, nullptr, 1024, 1024, 1024, 1.f);
  transpose_b16<<<dim3(16, 64), blk, 0, stream>>>(Vb, Vtb);
  // scores (256 blocks)
  gemm8<M_SCALE><<<dim3(16, 16), 512, 0, stream>>>(
      QKb, QKb + 1024, nullptr, nullptr, nullptr, nullptr, Sb, nullptr, nullptr, nullptr, 1024, 2048, 2048, 0.03125f);
  softmax_rows<<<4096, blk, 0, stream>>>(Sb);
  // PV split-K=2 raw partials: z=0 -> pvp0, z=1 -> pvp1 (via Cb3)   (128 blocks)
  gemm8<M_PVRAW><<<dim3(4, 16, 2), 512, 0, stream>>>(
      Sb, Vtb, nullptr, nullptr, nullptr, nullptr, nullptr, nullptr, (u16*)pvp1, pvp0, 2048, 4096, 4096, 1.f);
  // Zatp = f * (p0 + p1)
  pv_reduce<<<4096, blk, 0, stream>>>(pvp0, pvp1, fvb, Zatpb);
  // Z_EMA_f (f32, old template)   (512 blocks)
  gemm<M_F32, 64><<<dim3(16, 32), blk, 0, stream>>>(
      Zatpb, Wzab, b_z_at, nullptr, ZEMAf, 1024, 1024, 1024);
  // fused i + final
  final_kern<<<4096, 64, 0, stream>>>(REMAb, REMApb, ZEMAf, W_i, b_i, W_final, out);
}

// Round 11
// 338.577 us; speedup vs baseline: 1.0805x; 1.0805x over previous
//
#include <hip/hip_runtime.h>
#include <cstdint>
#include <cmath>

#define MB (1024ull * 1024ull)

typedef unsigned short u16;
typedef __attribute__((ext_vector_type(8))) short short8;
typedef __attribute__((ext_vector_type(4))) float f32x4;

enum { M_EMA = 0, M_ZRE = 1, M_QKVF = 2, M_SCALE = 3, M_PVMUL = 4, M_F32 = 5 };

__device__ __forceinline__ u16 f2b(float f) {
  union { float f; uint32_t u; } v; v.f = f;
  uint32_t r = v.u + 0x7FFFu + ((v.u >> 16) & 1u);
  return (u16)(r >> 16);
}
__device__ __forceinline__ float b2f(u16 u) {
  union { uint32_t u; float f; } v; v.u = ((uint32_t)u) << 16;
  return v.f;
}
__device__ __forceinline__ float tanh_fast(float x) {
  return 1.f - 2.f / (1.f + __expf(2.f * x));   // exact at both saturations
}
__device__ __forceinline__ float sigmoid_fast(float x) {
  return 1.f / (1.f + __expf(-x));
}

typedef __attribute__((address_space(3))) uint32_t lds_u32;
typedef const __attribute__((address_space(1))) uint32_t glb_u32;

__device__ __forceinline__ void gload16(const void* g, void* l) {
  __builtin_amdgcn_global_load_lds((glb_u32*)g, (lds_u32*)l, 16, 0, 0);
}

// ---------------- MFMA GEMM (round-6 structure): C = epi(A @ B^T [+ bias]) ----------------
// 64 x 128 tile, 4 waves (1x4, 64r x 32c each), 2-buffer LDS, stage(t+1) issued
// before compute(t), one __syncthreads per K-step. Chunk-XOR LDS swizzle.
// M_EMA: Wad/bias interleaved (alpha->even col, delta->odd col); epilogue pairs
//        lanes via shfl_xor(1), even lane computes REMA from R (fp32) -> Cb bf16 [4096][1024].
// M_QKVF: virtual N=4096; bn>=3072 computes f=sigmoid(A2@B2^T+bias2) -> Cb3.
// M_PVMUL: epilogue v *= aux (f-gate) -> Cb.
template <int MODE>
__global__ __launch_bounds__(256) void gemm(const u16* __restrict__ A,
                                            const u16* __restrict__ B,
                                            const float* __restrict__ bias,
                                            const u16* __restrict__ A2,
                                            const u16* __restrict__ B2,
                                            const float* __restrict__ bias2,
                                            const u16* __restrict__ auxb,
                                            u16* __restrict__ Cb,
                                            u16* __restrict__ Cb2,
                                            u16* __restrict__ Cb3,
                                            float* __restrict__ Cf,
                                            const float* __restrict__ R,
                                            int K, int lda, int ldb, float scale) {
  constexpr int NI = 4;
  constexpr int NJ = 2;
  __shared__ u16 As[2][64 * 32];
  __shared__ u16 Bs[2][128 * 32];
  const int tid = threadIdx.x;
  const int wid = tid >> 6, lane = tid & 63;

  // XCD-aware bijective block swizzle (grids are multiples of 8)
  const int gx = gridDim.x, nwg = gx * gridDim.y;
  int id = blockIdx.y * gx + blockIdx.x;
  if ((nwg & 7) == 0) id = (id & 7) * (nwg >> 3) + (id >> 3);
  const int bm = (id / gx) * 64, bn = (id % gx) * 128;
  const int colbase = wid * 32;

  const bool isf = (MODE == M_QKVF) && (bn >= 3072);
  const u16* Ab = isf ? A2 : A;
  const u16* Bb = isf ? B2 : B;
  const int bnl = isf ? bn - 3072 : bn;

  // staging: thread t -> row srow, swizzled 8-elem chunk
  const int srow = tid >> 2;
  const int schunk = (tid & 3) ^ ((srow >> 1) & 3);
  const u16* gA = Ab + (size_t)(bm + srow) * lda + schunk * 8;
  const u16* gB = Bb + (size_t)(bnl + srow) * ldb + schunk * 8;

  f32x4 acc[NI][NJ];
#pragma unroll
  for (int i = 0; i < NI; ++i)
#pragma unroll
    for (int j = 0; j < NJ; ++j) acc[i][j] = (f32x4){0.f, 0.f, 0.f, 0.f};

  const int ar = lane & 15;
  const int pch = (((lane >> 4) ^ ((ar >> 1) & 3))) * 8;  // swizzled k-chunk

  const int NT = K >> 5;

  auto stage = [&](int buf, int t) {
    const u16* a = gA + (size_t)t * 32;
    const u16* b = gB + (size_t)t * 32;
    gload16(a, &As[buf][wid * 512]);
    gload16(b, &Bs[buf][wid * 512]);
    gload16(b + (size_t)64 * ldb, &Bs[buf][wid * 512 + 2048]);
  };

  stage(0, 0);
  __syncthreads();
  int cur = 0;
  for (int t = 0; t < NT; ++t) {
    if (t + 1 < NT) stage(cur ^ 1, t + 1);  // prefetch overlaps compute below
    short8 af[NI], bf[NJ];
#pragma unroll
    for (int i = 0; i < NI; ++i)
      af[i] = *reinterpret_cast<const short8*>(&As[cur][(i * 16 + ar) * 32 + pch]);
#pragma unroll
    for (int j = 0; j < NJ; ++j)
      bf[j] = *reinterpret_cast<const short8*>(&Bs[cur][(colbase + j * 16 + ar) * 32 + pch]);
    __builtin_amdgcn_s_setprio(1);
#pragma unroll
    for (int i = 0; i < NI; ++i)
#pragma unroll
      for (int j = 0; j < NJ; ++j)
        acc[i][j] = __builtin_amdgcn_mfma_f32_16x16x32_bf16(af[i], bf[j], acc[i][j], 0, 0, 0);
    __builtin_amdgcn_s_setprio(0);
    __syncthreads();
    cur ^= 1;
  }

#pragma unroll
  for (int i = 0; i < NI; ++i) {
    const int rb = bm + i * 16 + (lane >> 4) * 4;
#pragma unroll
    for (int j = 0; j < NJ; ++j) {
      const int n = bn + colbase + j * 16 + ar;
#pragma unroll
      for (int r = 0; r < 4; ++r) {
        const int m = rb + r;
        float v = acc[i][j][r];
        if (MODE == M_EMA) {
          // v: interleaved alpha (even n) / delta (odd n), pre-activation
          v = tanh_fast(v + bias[n]);
          const float vp = __shfl_xor(v, 1);
          if ((lane & 1) == 0) {
            const int jc = n >> 1;                      // REMA column
            const float rt = R[(size_t)m * 1024 + jc];
            const float rp = (m > 0) ? R[(size_t)(m - 1) * 1024 + jc] : 0.f;
            const float rema = v * rt + (1.f - v) * vp * rp;
            Cb[(size_t)m * 1024 + jc] = f2b(rema);
          }
        } else if (MODE == M_ZRE) {
          v += bias[n];
          if (n < 1024) Cb[(size_t)m * 1024 + n] = f2b(v * sigmoid_fast(v));
          else Cb2[(size_t)m * 1024 + (n - 1024)] = f2b(v);
        } else if (MODE == M_QKVF) {
          if (isf) {
            const int nl = n - 3072;
            Cb3[(size_t)m * 1024 + nl] = f2b(sigmoid_fast(v + bias2[nl]));
          } else {
            v += bias[n];
            if (n < 2048) Cb[(size_t)m * 2048 + n] = f2b(v);
            else Cb2[(size_t)m * 1024 + (n - 2048)] = f2b(v);
          }
        } else if (MODE == M_SCALE) {
          Cb[(size_t)m * 4096 + n] = f2b(v * scale);
        } else if (MODE == M_PVMUL) {
          v *= b2f(auxb[(size_t)m * 1024 + n]);
          Cb[(size_t)m * 1024 + n] = f2b(v);
        } else if (MODE == M_F32) {
          Cf[(size_t)m * 1024 + n] = v + bias[n];
        }
      }
    }
  }
}

// ---------------- merged prep: weight conversions (Wad interleaved) + concat ----------------
__global__ __launch_bounds__(256) void convert_all(
    const float* __restrict__ s0, const float* __restrict__ s1, const float* __restrict__ s2,
    const float* __restrict__ s3, const float* __restrict__ s4, const float* __restrict__ s5,
    const float* __restrict__ s6, const float* __restrict__ s7, const float* __restrict__ s8,
    const float* __restrict__ R,
    u16* __restrict__ Wad, u16* __restrict__ Wze, u16* __restrict__ Wqkv,
    u16* __restrict__ Wfb, u16* __restrict__ Wzab, u16* __restrict__ Rc) {
  const int idx = blockIdx.x * 256 + threadIdx.x;
  if (idx >= 2883584) {
    // concat: Rc[m][k] = k<1024 ? (m>0 ? R[m-1][k] : 0) : R[m][k-1024]
    const int off = idx - 2883584;
    const int m = off >> 9;
    const int c = (off & 511) * 4;
    float4 v;
    if (c < 1024) {
      if (m > 0) v = *reinterpret_cast<const float4*>(&R[(size_t)(m - 1) * 1024 + c]);
      else v = make_float4(0.f, 0.f, 0.f, 0.f);
    } else {
      v = *reinterpret_cast<const float4*>(&R[(size_t)m * 1024 + (c - 1024)]);
    }
    ushort4 o; o.x = f2b(v.x); o.y = f2b(v.y); o.z = f2b(v.z); o.w = f2b(v.w);
    reinterpret_cast<ushort4*>(Rc)[off] = o;
    return;
  }
  const float* src; u16* dst; int off; int dstoff = -1;
  if (idx < 524288) {          // W_alpha -> even rows of Wad
    src = s0; dst = Wad; off = idx;
    dstoff = ((off >> 9) * 2) * 512 + (off & 511);
  } else if (idx < 1048576) {  // W_delta -> odd rows of Wad
    src = s1; dst = Wad; off = idx - 524288;
    dstoff = ((off >> 9) * 2 + 1) * 512 + (off & 511);
  }
  else if (idx < 1310720) { src = s2; dst = Wze;            off = idx - 1048576; }
  else if (idx < 1572864) { src = s3; dst = Wze + 1048576;  off = idx - 1310720; }
  else if (idx < 1835008) { src = s4; dst = Wqkv;           off = idx - 1572864; }
  else if (idx < 2097152) { src = s5; dst = Wqkv + 1048576; off = idx - 1835008; }
  else if (idx < 2359296) { src = s6; dst = Wqkv + 2097152; off = idx - 2097152; }
  else if (idx < 2621440) { src = s7; dst = Wfb;            off = idx - 2359296; }
  else                    { src = s8; dst = Wzab;           off = idx - 2621440; }
  if (dstoff < 0) dstoff = off;
  const float4 v = reinterpret_cast<const float4*>(src)[off];
  ushort4 o; o.x = f2b(v.x); o.y = f2b(v.y); o.z = f2b(v.z); o.w = f2b(v.w);
  reinterpret_cast<ushort4*>(dst)[dstoff] = o;
}

__global__ void copy_bias(const float* __restrict__ ba, const float* __restrict__ bd,
                          const float* __restrict__ bz, const float* __restrict__ be,
                          const float* __restrict__ bq, const float* __restrict__ bk,
                          const float* __restrict__ bv,
                          float* __restrict__ bad, float* __restrict__ bze,
                          float* __restrict__ bqkv) {
  const int t = threadIdx.x;
  if (blockIdx.x == 0) {        // interleave alpha bias -> even slots
#pragma unroll
    for (int k = 0; k < 4; ++k) bad[2 * (t + 256 * k)] = ba[t + 256 * k];
    return;
  }
  if (blockIdx.x == 1) {        // delta bias -> odd slots
#pragma unroll
    for (int k = 0; k < 4; ++k) bad[2 * (t + 256 * k) + 1] = bd[t + 256 * k];
    return;
  }
  const float4* src; float4* dst;
  switch (blockIdx.x) {
    case 2: src = (const float4*)bz; dst = (float4*)bze; break;
    case 3: src = (const float4*)be; dst = (float4*)(bze + 1024); break;
    case 4: src = (const float4*)bq; dst = (float4*)bqkv; break;
    case 5: src = (const float4*)bk; dst = (float4*)(bqkv + 1024); break;
    default: src = (const float4*)bv; dst = (float4*)(bqkv + 2048); break;
  }
  dst[t] = src[t];
}

__device__ __forceinline__ float waveMax(float v) {
#pragma unroll
  for (int o = 32; o; o >>= 1) v = fmaxf(v, __shfl_down(v, o));
  return v;
}
__device__ __forceinline__ float waveSum(float v) {
#pragma unroll
  for (int o = 32; o; o >>= 1) v += __shfl_down(v, o);
  return v;
}

__global__ __launch_bounds__(256) void softmax_rows(u16* __restrict__ S) {
  u16* p = S + (size_t)blockIdx.x * 4096;
  const int tid = threadIdx.x;
  float v[16];
#pragma unroll
  for (int j = 0; j < 4; ++j) {
    const ushort4 t = *reinterpret_cast<const ushort4*>(&p[tid * 4 + 1024 * j]);
    v[4 * j + 0] = b2f(t.x); v[4 * j + 1] = b2f(t.y);
    v[4 * j + 2] = b2f(t.z); v[4 * j + 3] = b2f(t.w);
  }
  float mx = -INFINITY;
#pragma unroll
  for (int j = 0; j < 16; ++j) mx = fmaxf(mx, v[j]);
  __shared__ float red[4];
  const float wm = waveMax(mx);
  if ((tid & 63) == 0) red[tid >> 6] = wm;
  __syncthreads();
  mx = fmaxf(fmaxf(red[0], red[1]), fmaxf(red[2], red[3]));
  __syncthreads();
  float sum = 0.f;
#pragma unroll
  for (int j = 0; j < 16; ++j) { v[j] = __expf(v[j] - mx); sum += v[j]; }
  const float ws_ = waveSum(sum);
  if ((tid & 63) == 0) red[tid >> 6] = ws_;
  __syncthreads();
  const float inv = 1.f / (red[0] + red[1] + red[2] + red[3]);
#pragma unroll
  for (int j = 0; j < 4; ++j) {
    ushort4 t;
    t.x = f2b(v[4 * j + 0] * inv); t.y = f2b(v[4 * j + 1] * inv);
    t.z = f2b(v[4 * j + 2] * inv); t.w = f2b(v[4 * j + 3] * inv);
    *reinterpret_cast<ushort4*>(&p[tid * 4 + 1024 * j]) = t;
  }
}

__global__ __launch_bounds__(256) void transpose_b16(const u16* __restrict__ V,
                                                     u16* __restrict__ Vt) {
  __shared__ u16 t[64][72];
  const int bn = blockIdx.x * 64;
  const int bk = blockIdx.y * 64;
  const int tx = threadIdx.x & 15, ty = threadIdx.x >> 4;
#pragma unroll
  for (int i = 0; i < 64; i += 16) {
    const ushort4 v = *reinterpret_cast<const ushort4*>(&V[(size_t)(bk + ty + i) * 1024 + bn + tx * 4]);
    t[ty + i][tx * 4 + 0] = v.x; t[ty + i][tx * 4 + 1] = v.y;
    t[ty + i][tx * 4 + 2] = v.z; t[ty + i][tx * 4 + 3] = v.w;
  }
  __syncthreads();
#pragma unroll
  for (int i = 0; i < 64; i += 16) {
    ushort4 w;
    w.x = t[tx * 4 + 0][ty + i]; w.y = t[tx * 4 + 1][ty + i];
    w.z = t[tx * 4 + 2][ty + i]; w.w = t[tx * 4 + 3][ty + i];
    *reinterpret_cast<ushort4*>(&Vt[(size_t)(bn + ty + i) * 4096 + bk + tx * 4]) = w;
  }
}

// fused: i = tanh(REMA . Wi + bi); out = sigmoid( (i*tanh(REMAp+ZEMAf)+(1-i)*REMAp) . Wfin )
__global__ void final_kern(const u16* __restrict__ REMAb, const u16* __restrict__ REMApb,
                           const float* __restrict__ ZEMAf,
                           const float* __restrict__ Wi, const float* __restrict__ bi,
                           const float* __restrict__ Wfin, float* __restrict__ out) {
  const int m = blockIdx.x, l = threadIdx.x;
  float si = 0.f;
#pragma unroll
  for (int j = 0; j < 16; ++j) {
    const int n = l + 64 * j;
    si += b2f(REMAb[(size_t)m * 1024 + n]) * Wi[n];
  }
#pragma unroll
  for (int o = 32; o; o >>= 1) si += __shfl_xor(si, o);
  const float im = tanh_fast(si + bi[0]);
  float s = 0.f;
#pragma unroll
  for (int j = 0; j < 16; ++j) {
    const int n = l + 64 * j;
    const float rp = b2f(REMApb[(size_t)m * 1024 + n]);
    const float zf = im * tanh_fast(rp + ZEMAf[(size_t)m * 1024 + n]) + (1.f - im) * rp;
    s += zf * Wfin[n];
  }
#pragma unroll
  for (int o = 32; o; o >>= 1) s += __shfl_down(s, o);
  if (l == 0) out[m] = sigmoid_fast(s);
}

extern "C" void kernel_launch(void* const* d_in, const int* in_sizes, int n_in,
                              void* d_out, int out_size, void* d_ws, size_t ws_size,
                              hipStream_t stream) {
  const float* R       = (const float*)d_in[0];
  const float* W_alpha = (const float*)d_in[1];  const float* b_alpha = (const float*)d_in[2];
  const float* W_delta = (const float*)d_in[3];  const float* b_delta = (const float*)d_in[4];
  const float* W_q     = (const float*)d_in[5];  const float* b_q     = (const float*)d_in[6];
  const float* W_k     = (const float*)d_in[7];  const float* b_k     = (const float*)d_in[8];
  const float* W_v     = (const float*)d_in[9];  const float* b_v     = (const float*)d_in[10];
  const float* W_z     = (const float*)d_in[11]; const float* b_z     = (const float*)d_in[12];
  const float* W_f     = (const float*)d_in[13]; const float* b_f     = (const float*)d_in[14];
  const float* W_EMA   = (const float*)d_in[15]; const float* b_EMA   = (const float*)d_in[16];
  const float* W_z_at  = (const float*)d_in[17]; const float* b_z_at  = (const float*)d_in[18];
  const float* W_i     = (const float*)d_in[19]; const float* b_i     = (const float*)d_in[20];
  const float* W_final = (const float*)d_in[21];
  float* out = (float*)d_out;
  uint8_t* w8 = (uint8_t*)d_ws;

  // ---- workspace layout (time-multiplexed), peak ~110 MB ----
  u16*   Rc     = (u16*)(w8 + 0 * MB);     // [0,16)  prep -> adGEMM
  u16*   Zb     = (u16*)(w8 + 0 * MB);     // [0,8)   zre -> qkvf
  u16*   Zatpb  = (u16*)(w8 + 0 * MB);     // [0,8)   PV -> zemaf
  u16*   REMApb = (u16*)(w8 + 8 * MB);     // [8,16)  zre -> final
  u16*   Wad    = (u16*)(w8 + 16 * MB);    // [16,24) prep -> adGEMM (interleaved)
  u16*   fvb    = (u16*)(w8 + 16 * MB);    // [16,24) qkvf -> PV
  float* ZEMAf  = (float*)(w8 + 24 * MB);  // [24,40) zemaf -> final
  u16*   Wqkv   = (u16*)(w8 + 40 * MB);    // [40,46) prep -> qkvf
  u16*   Vtb    = (u16*)(w8 + 40 * MB);    // [40,48) transpose -> PV
  u16*   Wze    = (u16*)(w8 + 46 * MB);    // [46,50) prep -> zre
  u16*   Wfb    = (u16*)(w8 + 50 * MB);    // [50,52) prep -> qkvf(f)
  u16*   Wzab   = (u16*)(w8 + 52 * MB);    // [52,54) prep -> zemaf
  u16*   REMAb  = (u16*)(w8 + 54 * MB);    // [54,62) adGEMM -> end
  u16*   QKb    = (u16*)(w8 + 62 * MB);    // [62,78) qkvf -> scores
  u16*   Vb     = (u16*)(w8 + 78 * MB);    // [78,86) qkvf -> transpose
  u16*   Sb     = (u16*)(w8 + 78 * MB);    // [78,110) scores -> PV
  float* bad    = (float*)(w8 + 110 * MB + 64 * 1024);
  float* bze    = bad + 2048;
  float* bqkv   = bze + 2048;

  const dim3 blk(256);
  convert_all<<<19456, blk, 0, stream>>>(W_alpha, W_delta, W_z, W_EMA, W_q, W_k, W_v, W_f, W_z_at,
                                         R, Wad, Wze, Wqkv, Wfb, Wzab, Rc);
  copy_bias<<<7, blk, 0, stream>>>(b_alpha, b_delta, b_z, b_EMA, b_q, b_k, b_v, bad, bze, bqkv);

  // ad + fused EMA: REMAb = alpha*r_t + (1-alpha)*delta*r_prev   (1024 blocks)
  gemm<M_EMA><<<dim3(16, 64), blk, 0, stream>>>(
      Rc, Wad, bad, nullptr, nullptr, nullptr, nullptr, REMAb, nullptr, nullptr, nullptr, R, 2048, 2048, 2048, 1.f);
  // Z | REMAp fused: N=2048 (silu -> Zb, plain -> REMApb)   (1024 blocks)
  gemm<M_ZRE><<<dim3(16, 64), blk, 0, stream>>>(
      REMAb, Wze, bze, nullptr, nullptr, nullptr, nullptr, Zb, REMApb, nullptr, nullptr, nullptr, 1024, 1024, 1024, 1.f);
  // QKV + f merged: virtual N=4096 (QK->QKb, V->Vb, f->fvb)   (2048 blocks)
  gemm<M_QKVF><<<dim3(32, 64), blk, 0, stream>>>(
      Zb, Wqkv, bqkv, REMApb, Wfb, b_f, nullptr, QKb, Vb, fvb, nullptr, nullptr, 1024, 1024, 1024, 1.f);
  transpose_b16<<<dim3(16, 64), blk, 0, stream>>>(Vb, Vtb);
  // scores (2048 blocks)
  gemm<M_SCALE><<<dim3(32, 64), blk, 0, stream>>>(
      QKb, QKb + 1024, nullptr, nullptr, nullptr, nullptr, nullptr, Sb, nullptr, nullptr, nullptr, nullptr, 1024, 2048, 2048, 0.03125f);
  softmax_rows<<<4096, blk, 0, stream>>>(Sb);
  // PV with fused f-gate: Zatp = f * (P @ Vt)   (512 blocks, K=4096)
  gemm<M_PVMUL><<<dim3(8, 64), blk, 0, stream>>>(
      Sb, Vtb, nullptr, nullptr, nullptr, nullptr, fvb, Zatpb, nullptr, nullptr, nullptr, nullptr, 4096, 4096, 4096, 1.f);
  // Z_EMA_f (f32)   (512 blocks)
  gemm<M_F32><<<dim3(8, 64), blk, 0, stream>>>(
      Zatpb, Wzab, b_z_at, nullptr, nullptr, nullptr, nullptr, nullptr, nullptr, nullptr, ZEMAf, nullptr, 1024, 1024, 1024, 1.f);
  // fused i + final
  final_kern<<<4096, 64, 0, stream>>>(REMAb, REMApb, ZEMAf, W_i, b_i, W_final, out);
}